// Round 6
// baseline (617.862 us; speedup 1.0000x reference)
//
#include <hip/hip_runtime.h>

#define NN 15360        // total nodes
#define NCR 11520       // compacted H1 rows: 45 per graph (q 0..14, c 30..59)
#define EPG 135         // active edges per graph, contiguous per graph
#define BATCH 256
#define D 128
#define TT 64
#define NPG 60
#define NCC 30
#define NQQ 15
#define NPROP 5
#define SKI 10

typedef __attribute__((ext_vector_type(8))) short bf16x8;
typedef __attribute__((ext_vector_type(4))) float f32x4;

__device__ __forceinline__ float bf2f(unsigned short u) {
    union { float f; unsigned int i; } t;
    t.i = ((unsigned int)u) << 16;
    return t.f;
}
__device__ __forceinline__ unsigned short f2bf(float f) {
    union { float f; unsigned int i; } t;
    t.f = f;
    unsigned int r = t.i + 0x7fffu + ((t.i >> 16) & 1u);
    return (unsigned short)(r >> 16);
}
// split v = hi + lo with |lo| <= 2^-9 |v|; residual after pair ~2^-18
__device__ __forceinline__ void split_bf(float v, unsigned short& hi, unsigned short& lo) {
    hi = f2bf(v);
    lo = f2bf(v - bf2f(hi));
}

// ---------------- node encode: h[i,d] = nf[i]*w[d]+b[d]; fp32 + split ----------------
__global__ void k_encode(const float* __restrict__ nf, const float* __restrict__ w,
                         const float* __restrict__ b, float* __restrict__ h,
                         unsigned short* __restrict__ h_hi, unsigned short* __restrict__ h_lo) {
    int idx = blockIdx.x * 256 + threadIdx.x;
    if (idx >= NN * D) return;
    int d = idx & (D - 1);
    int i = idx >> 7;
    float v = nf[i] * w[d] + b[d];
    h[idx] = v;
    unsigned short hi, lo;
    split_bf(v, hi, lo);
    h_hi[idx] = hi;
    h_lo[idx] = lo;
}

// ---------------- edge-constant precompute: uv (512 fp32) ----------------
__global__ void k_prep_uv(const float* __restrict__ ew, const float* __restrict__ eb,
                          const float* __restrict__ w1, const float* __restrict__ b1,
                          float* __restrict__ uv) {
    int t = threadIdx.x;  // 0..255
    float u = 0.f, v = 0.f;
    for (int d = 0; d < D; ++d) {
        float wv = w1[(256 + d) * 256 + t];
        u += ew[d] * wv;
        v += eb[d] * wv;
    }
    uv[t] = u;
    uv[256 + t] = v + b1[t];
}

// ---------------- weight prep: transpose to [n][k], split into hi/lo bf16 -----------
__global__ void k_prep_w(const float* __restrict__ mw1, const float* __restrict__ mw2,
                         const float* __restrict__ uw1, const float* __restrict__ uw2,
                         unsigned short* __restrict__ w1th, unsigned short* __restrict__ w1tl,
                         unsigned short* __restrict__ w2th, unsigned short* __restrict__ w2tl,
                         unsigned short* __restrict__ uw1th, unsigned short* __restrict__ uw1tl,
                         unsigned short* __restrict__ uw2th, unsigned short* __restrict__ uw2tl) {
    int idx = blockIdx.x * 256 + threadIdx.x;
    float v;
    unsigned short *ph, *pl;
    int o;
    if (idx < 65536) {  // w1t [512][128]
        int n = idx >> 7, k = idx & 127;
        v = (n < 256) ? mw1[k * 256 + n] : mw1[(128 + k) * 256 + (n - 256)];
        ph = w1th; pl = w1tl; o = idx;
    } else if (idx < 98304) {  // w2t [128][256]
        o = idx - 65536;
        int n = o >> 8, k = o & 255;
        v = mw2[k * 128 + n];
        ph = w2th; pl = w2tl;
    } else if (idx < 163840) {  // uw1t [256][256]
        o = idx - 98304;
        int n = o >> 8, k = o & 255;
        v = uw1[k * 256 + n];
        ph = uw1th; pl = uw1tl;
    } else if (idx < 196608) {  // uw2t [128][256]
        o = idx - 163840;
        int n = o >> 8, k = o & 255;
        v = uw2[k * 128 + n];
        ph = uw2th; pl = uw2tl;
    } else {
        return;
    }
    unsigned short hi, lo;
    split_bf(v, hi, lo);
    ph[o] = hi;
    pl[o] = lo;
}

// ===== dense split-MFMA GEMMs: BM=64, BN=64, BK=64, 4 waves (2x2), 3-term =====
// A in LDS (row stride 72 ushorts, conflict-free b128); B fragments straight from
// global (weights are L2-resident and shared by all blocks).

// ---- H1c(11520 x 512) fp32 = gather(h) @ w1t^T ----
__global__ __launch_bounds__(256) void k_h1c_mf(const unsigned short* __restrict__ h_hi,
                                                const unsigned short* __restrict__ h_lo,
                                                const unsigned short* __restrict__ w1th,
                                                const unsigned short* __restrict__ w1tl,
                                                float* __restrict__ H1c) {
    __shared__ unsigned short AsH[64 * 72], AsL[64 * 72];
    __shared__ int rowNode[64];
    int m0 = blockIdx.x * 64, n0 = blockIdx.y * 64;
    int tid = threadIdx.x;
    int lane = tid & 63, wid = tid >> 6;
    int wr = wid >> 1, wc = wid & 1;
    if (tid < 64) {
        int m = m0 + tid;
        int g = m / 45;
        int p = m - g * 45;
        rowNode[tid] = g * 60 + (p < 15 ? p : p + 15);
    }
    f32x4 acc[2][2] = {};
    for (int k0 = 0; k0 < 128; k0 += 64) {
        __syncthreads();
        for (int c = tid; c < 512; c += 256) {
            int row = c >> 3, kc = c & 7;
            size_t asrc = (size_t)rowNode[row] * D + k0 + kc * 8;
            *(uint4*)&AsH[row * 72 + kc * 8] = *(const uint4*)&h_hi[asrc];
            *(uint4*)&AsL[row * 72 + kc * 8] = *(const uint4*)&h_lo[asrc];
        }
        __syncthreads();
#pragma unroll
        for (int kk = 0; kk < 2; ++kk) {
            int koff = kk * 32 + (lane >> 4) * 8;
            bf16x8 ah[2], al[2], bh[2], bl[2];
#pragma unroll
            for (int i = 0; i < 2; i++) {
                int r = (wr * 32 + i * 16 + (lane & 15)) * 72 + koff;
                ah[i] = *(bf16x8*)&AsH[r];
                al[i] = *(bf16x8*)&AsL[r];
            }
#pragma unroll
            for (int j = 0; j < 2; j++) {
                size_t br = (size_t)(n0 + wc * 32 + j * 16 + (lane & 15)) * 128 + k0 + koff;
                bh[j] = *(const bf16x8*)&w1th[br];
                bl[j] = *(const bf16x8*)&w1tl[br];
            }
#pragma unroll
            for (int i = 0; i < 2; i++)
#pragma unroll
                for (int j = 0; j < 2; j++) {
                    acc[i][j] = __builtin_amdgcn_mfma_f32_16x16x32_bf16(ah[i], bh[j], acc[i][j], 0, 0, 0);
                    acc[i][j] = __builtin_amdgcn_mfma_f32_16x16x32_bf16(al[i], bh[j], acc[i][j], 0, 0, 0);
                    acc[i][j] = __builtin_amdgcn_mfma_f32_16x16x32_bf16(ah[i], bl[j], acc[i][j], 0, 0, 0);
                }
        }
    }
    int rloc = (lane >> 4) * 4;
#pragma unroll
    for (int i = 0; i < 2; i++)
#pragma unroll
        for (int j = 0; j < 2; j++) {
            int col = n0 + wc * 32 + j * 16 + (lane & 15);
#pragma unroll
            for (int r = 0; r < 4; r++) {
                int m = m0 + wr * 32 + i * 16 + rloc + r;
                H1c[(size_t)m * 512 + col] = acc[i][j][r];
            }
        }
}

// ---- U(15360 x 256) = relu([agg0+agg1 | h] @ uw1t^T + b1), split out ----
__global__ __launch_bounds__(256) void k_upd1_mf(const float* __restrict__ agg0,
                                                 const float* __restrict__ agg1,
                                                 const unsigned short* __restrict__ h_hi,
                                                 const unsigned short* __restrict__ h_lo,
                                                 const unsigned short* __restrict__ uw1th,
                                                 const unsigned short* __restrict__ uw1tl,
                                                 const float* __restrict__ b1,
                                                 unsigned short* __restrict__ Ub_hi,
                                                 unsigned short* __restrict__ Ub_lo) {
    __shared__ unsigned short AsH[64 * 72], AsL[64 * 72];
    int m0 = blockIdx.x * 64, n0 = blockIdx.y * 64;
    int tid = threadIdx.x;
    int lane = tid & 63, wid = tid >> 6;
    int wr = wid >> 1, wc = wid & 1;
    f32x4 acc[2][2] = {};
    for (int k0 = 0; k0 < 256; k0 += 64) {
        __syncthreads();
        if (k0 < 128) {
            for (int c = tid; c < 512; c += 256) {
                int row = c >> 3, kc = c & 7;
                size_t s = (size_t)(m0 + row) * D + k0 + kc * 8;
                float4 a0 = *(const float4*)&agg0[s];
                float4 a1 = *(const float4*)&agg0[s + 4];
                float4 c0 = *(const float4*)&agg1[s];
                float4 c1 = *(const float4*)&agg1[s + 4];
                float v[8] = {a0.x + c0.x, a0.y + c0.y, a0.z + c0.z, a0.w + c0.w,
                              a1.x + c1.x, a1.y + c1.y, a1.z + c1.z, a1.w + c1.w};
                unsigned int ph[4], pl[4];
#pragma unroll
                for (int t = 0; t < 4; t++) {
                    unsigned short h0, l0, h1, l1;
                    split_bf(v[2 * t], h0, l0);
                    split_bf(v[2 * t + 1], h1, l1);
                    ph[t] = (unsigned int)h0 | ((unsigned int)h1 << 16);
                    pl[t] = (unsigned int)l0 | ((unsigned int)l1 << 16);
                }
                *(uint4*)&AsH[row * 72 + kc * 8] = make_uint4(ph[0], ph[1], ph[2], ph[3]);
                *(uint4*)&AsL[row * 72 + kc * 8] = make_uint4(pl[0], pl[1], pl[2], pl[3]);
            }
        } else {
            for (int c = tid; c < 512; c += 256) {
                int row = c >> 3, kc = c & 7;
                size_t s = (size_t)(m0 + row) * D + (k0 - 128) + kc * 8;
                *(uint4*)&AsH[row * 72 + kc * 8] = *(const uint4*)&h_hi[s];
                *(uint4*)&AsL[row * 72 + kc * 8] = *(const uint4*)&h_lo[s];
            }
        }
        __syncthreads();
#pragma unroll
        for (int kk = 0; kk < 2; ++kk) {
            int koff = kk * 32 + (lane >> 4) * 8;
            bf16x8 ah[2], al[2], bh[2], bl[2];
#pragma unroll
            for (int i = 0; i < 2; i++) {
                int r = (wr * 32 + i * 16 + (lane & 15)) * 72 + koff;
                ah[i] = *(bf16x8*)&AsH[r];
                al[i] = *(bf16x8*)&AsL[r];
            }
#pragma unroll
            for (int j = 0; j < 2; j++) {
                size_t br = (size_t)(n0 + wc * 32 + j * 16 + (lane & 15)) * 256 + k0 + koff;
                bh[j] = *(const bf16x8*)&uw1th[br];
                bl[j] = *(const bf16x8*)&uw1tl[br];
            }
#pragma unroll
            for (int i = 0; i < 2; i++)
#pragma unroll
                for (int j = 0; j < 2; j++) {
                    acc[i][j] = __builtin_amdgcn_mfma_f32_16x16x32_bf16(ah[i], bh[j], acc[i][j], 0, 0, 0);
                    acc[i][j] = __builtin_amdgcn_mfma_f32_16x16x32_bf16(al[i], bh[j], acc[i][j], 0, 0, 0);
                    acc[i][j] = __builtin_amdgcn_mfma_f32_16x16x32_bf16(ah[i], bl[j], acc[i][j], 0, 0, 0);
                }
        }
    }
    int rloc = (lane >> 4) * 4;
#pragma unroll
    for (int i = 0; i < 2; i++)
#pragma unroll
        for (int j = 0; j < 2; j++) {
            int col = n0 + wc * 32 + j * 16 + (lane & 15);
            float bias = b1[col];
#pragma unroll
            for (int r = 0; r < 4; r++) {
                int m = m0 + wr * 32 + i * 16 + rloc + r;
                float v = fmaxf(acc[i][j][r] + bias, 0.f);
                unsigned short hi, lo;
                split_bf(v, hi, lo);
                Ub_hi[(size_t)m * 256 + col] = hi;
                Ub_lo[(size_t)m * 256 + col] = lo;
            }
        }
}

// ---- h(15360x128) += U @ uw2t^T + b2 ; fp32 residual + re-split h ----
__global__ __launch_bounds__(256) void k_upd2_mf(const unsigned short* __restrict__ Ub_hi,
                                                 const unsigned short* __restrict__ Ub_lo,
                                                 const unsigned short* __restrict__ uw2th,
                                                 const unsigned short* __restrict__ uw2tl,
                                                 const float* __restrict__ b2,
                                                 float* __restrict__ h,
                                                 unsigned short* __restrict__ h_hi,
                                                 unsigned short* __restrict__ h_lo) {
    __shared__ unsigned short AsH[64 * 72], AsL[64 * 72];
    int m0 = blockIdx.x * 64, n0 = blockIdx.y * 64;
    int tid = threadIdx.x;
    int lane = tid & 63, wid = tid >> 6;
    int wr = wid >> 1, wc = wid & 1;
    f32x4 acc[2][2] = {};
    for (int k0 = 0; k0 < 256; k0 += 64) {
        __syncthreads();
        for (int c = tid; c < 512; c += 256) {
            int row = c >> 3, kc = c & 7;
            size_t s = (size_t)(m0 + row) * 256 + k0 + kc * 8;
            *(uint4*)&AsH[row * 72 + kc * 8] = *(const uint4*)&Ub_hi[s];
            *(uint4*)&AsL[row * 72 + kc * 8] = *(const uint4*)&Ub_lo[s];
        }
        __syncthreads();
#pragma unroll
        for (int kk = 0; kk < 2; ++kk) {
            int koff = kk * 32 + (lane >> 4) * 8;
            bf16x8 ah[2], al[2], bh[2], bl[2];
#pragma unroll
            for (int i = 0; i < 2; i++) {
                int r = (wr * 32 + i * 16 + (lane & 15)) * 72 + koff;
                ah[i] = *(bf16x8*)&AsH[r];
                al[i] = *(bf16x8*)&AsL[r];
            }
#pragma unroll
            for (int j = 0; j < 2; j++) {
                size_t br = (size_t)(n0 + wc * 32 + j * 16 + (lane & 15)) * 256 + k0 + koff;
                bh[j] = *(const bf16x8*)&uw2th[br];
                bl[j] = *(const bf16x8*)&uw2tl[br];
            }
#pragma unroll
            for (int i = 0; i < 2; i++)
#pragma unroll
                for (int j = 0; j < 2; j++) {
                    acc[i][j] = __builtin_amdgcn_mfma_f32_16x16x32_bf16(ah[i], bh[j], acc[i][j], 0, 0, 0);
                    acc[i][j] = __builtin_amdgcn_mfma_f32_16x16x32_bf16(al[i], bh[j], acc[i][j], 0, 0, 0);
                    acc[i][j] = __builtin_amdgcn_mfma_f32_16x16x32_bf16(ah[i], bl[j], acc[i][j], 0, 0, 0);
                }
        }
    }
    int rloc = (lane >> 4) * 4;
#pragma unroll
    for (int i = 0; i < 2; i++)
#pragma unroll
        for (int j = 0; j < 2; j++) {
            int col = n0 + wc * 32 + j * 16 + (lane & 15);
            float bias = b2[col];
#pragma unroll
            for (int r = 0; r < 4; r++) {
                int m = m0 + wr * 32 + i * 16 + rloc + r;
                size_t o = (size_t)m * D + col;
                float v = h[o] + acc[i][j][r] + bias;
                h[o] = v;
                unsigned short hi, lo;
                split_bf(v, hi, lo);
                h_hi[o] = hi;
                h_lo[o] = lo;
            }
        }
}

// ===== per-graph edge pass, split-MFMA, M-split: block=(graph, half) =====
__global__ __launch_bounds__(256) void k_edge_mf(const float* __restrict__ H1c,
                                                 const float* __restrict__ uv,
                                                 const int* __restrict__ fr,
                                                 const int* __restrict__ to,
                                                 const float* __restrict__ ef,
                                                 const float* __restrict__ mfi,
                                                 const unsigned short* __restrict__ w2th,
                                                 const unsigned short* __restrict__ w2tl,
                                                 const float* __restrict__ b2,
                                                 float* __restrict__ agg0,
                                                 float* __restrict__ agg1) {
    __shared__ unsigned short AsH[80 * 40], AsL[80 * 40];  // stride 80B (5x16B)
    __shared__ float aggl[NPG][128];
    __shared__ float uvl[512];
    __shared__ int cfs[80], ctc[80], ctl[80];
    __shared__ float efs[80], ms_[80];
    int g = blockIdx.x;
    int half = blockIdx.y;
    int tid = threadIdx.x;
    int lane = tid & 63, wid = tid >> 6;
    int cnt = half ? (EPG - 72) : 72;  // 63 or 72
    int ebase = g * EPG + half * 72;
    if (tid < 80) {
        if (tid < cnt) {
            int f = fr[ebase + tid] - g * 60;
            int t = to[ebase + tid] - g * 60;
            cfs[tid] = g * 45 + (f < 15 ? f : f - 15);
            ctc[tid] = g * 45 + (t < 15 ? t : t - 15);
            ctl[tid] = t;
            efs[tid] = ef[ebase + tid];
            ms_[tid] = mfi[ebase + tid];
        } else {
            cfs[tid] = g * 45; ctc[tid] = g * 45; ctl[tid] = 0;
            efs[tid] = 0.f; ms_[tid] = 0.f;
        }
    }
    for (int i = tid; i < 512; i += 256) uvl[i] = uv[i];
    for (int i = tid; i < NPG * 128; i += 256) (&aggl[0][0])[i] = 0.f;
    f32x4 acc[5][2] = {};
    for (int ks = 0; ks < 8; ++ks) {
        __syncthreads();
        for (int c = tid; c < 320; c += 256) {
            int row = c >> 2, kc = c & 3;
            int k = ks * 32 + kc * 8;
            const float* pf = H1c + (size_t)cfs[row] * 512 + k;
            const float* pt = H1c + (size_t)ctc[row] * 512 + 256 + k;
            float e_ = efs[row];
            float4 f0 = *(const float4*)pf, f1 = *(const float4*)(pf + 4);
            float4 t0 = *(const float4*)pt, t1 = *(const float4*)(pt + 4);
            float zf[8] = {f0.x + t0.x, f0.y + t0.y, f0.z + t0.z, f0.w + t0.w,
                           f1.x + t1.x, f1.y + t1.y, f1.z + t1.z, f1.w + t1.w};
            unsigned int ph[4], pl[4];
#pragma unroll
            for (int t = 0; t < 4; t++) {
                float z0 = fmaxf(zf[2 * t]     + e_ * uvl[k + 2 * t]     + uvl[256 + k + 2 * t], 0.f);
                float z1 = fmaxf(zf[2 * t + 1] + e_ * uvl[k + 2 * t + 1] + uvl[256 + k + 2 * t + 1], 0.f);
                unsigned short h0, l0, h1, l1;
                split_bf(z0, h0, l0);
                split_bf(z1, h1, l1);
                ph[t] = (unsigned int)h0 | ((unsigned int)h1 << 16);
                pl[t] = (unsigned int)l0 | ((unsigned int)l1 << 16);
            }
            *(uint4*)&AsH[row * 40 + kc * 8] = make_uint4(ph[0], ph[1], ph[2], ph[3]);
            *(uint4*)&AsL[row * 40 + kc * 8] = make_uint4(pl[0], pl[1], pl[2], pl[3]);
        }
        __syncthreads();
        int koff = (lane >> 4) * 8;
        bf16x8 bh[2], bl[2];
#pragma unroll
        for (int j = 0; j < 2; j++) {
            size_t br = (size_t)(wid * 32 + j * 16 + (lane & 15)) * 256 + ks * 32 + koff;
            bh[j] = *(const bf16x8*)&w2th[br];
            bl[j] = *(const bf16x8*)&w2tl[br];
        }
#pragma unroll
        for (int i = 0; i < 5; i++) {
            int r = (i * 16 + (lane & 15)) * 40 + koff;
            bf16x8 ah = *(bf16x8*)&AsH[r];
            bf16x8 al = *(bf16x8*)&AsL[r];
#pragma unroll
            for (int j = 0; j < 2; j++) {
                acc[i][j] = __builtin_amdgcn_mfma_f32_16x16x32_bf16(ah, bh[j], acc[i][j], 0, 0, 0);
                acc[i][j] = __builtin_amdgcn_mfma_f32_16x16x32_bf16(al, bh[j], acc[i][j], 0, 0, 0);
                acc[i][j] = __builtin_amdgcn_mfma_f32_16x16x32_bf16(ah, bl[j], acc[i][j], 0, 0, 0);
            }
        }
    }
    __syncthreads();
    int rloc = (lane >> 4) * 4;
#pragma unroll
    for (int i = 0; i < 5; i++)
#pragma unroll
        for (int j = 0; j < 2; j++) {
            int col = wid * 32 + j * 16 + (lane & 15);
            float bias = b2[col];
#pragma unroll
            for (int r = 0; r < 4; r++) {
                int e = i * 16 + rloc + r;
                if (e < cnt) {
                    float val = (acc[i][j][r] + bias) * ms_[e];
                    atomicAdd(&aggl[ctl[e]][col], val);
                }
            }
        }
    __syncthreads();
    float* dst = half ? agg1 : agg0;
    for (int idx = tid; idx < NPG * 128; idx += 256) {
        int r = idx >> 7, c = idx & 127;
        dst[(size_t)(g * NPG + r) * D + c] = aggl[r][c];
    }
}

// ===== fused per-graph tail: transform + Sinkhorn + score =====
// 256 threads/graph. Wave-parallel lse via 8-lane groups; padded LDS (no conflicts).
__global__ __launch_bounds__(256) void k_tail(const float* __restrict__ h,
                                              const float* __restrict__ f1w,
                                              const float* __restrict__ f1b,
                                              const float* __restrict__ f2w,
                                              const float* __restrict__ f2b,
                                              float* __restrict__ out) {
    __shared__ float ce[NCC][D];          // c_emb rows (reused in moved)
    __shared__ float qe[NQQ][D];          // q rows 0..14 (transform inputs)
    __shared__ float hid[45][TT];         // rows 0..14 = q, 15..44 = c
    __shared__ float tq[NQQ][TT + 2];     // pad 66 -> 2-way max on QK^T
    __shared__ float tc[NCC][TT + 2];
    __shared__ float la[NCC][33];         // pad 33 -> conflict-free rows AND cols
    __shared__ float red[256];
    int g = blockIdx.x;
    int tid = threadIdx.x;
    for (int idx = tid; idx < NCC * D; idx += 256) {
        int c = idx >> 7, d = idx & 127;
        ce[c][d] = h[(size_t)(g * NPG + NCC + c) * D + d];
    }
    for (int idx = tid; idx < NQQ * D; idx += 256) {
        int r = idx >> 7, d = idx & 127;
        qe[r][d] = h[(size_t)(g * NPG + r) * D + d];
    }
    __syncthreads();
    // hid = relu(row @ ft1 + b1), 45 rows x 64
    for (int idx = tid; idx < 45 * TT; idx += 256) {
        int r = idx >> 6, j = idx & 63;
        const float* src = (r < NQQ) ? qe[r] : ce[r - NQQ];
        float s = f1b[j];
#pragma unroll 4
        for (int k = 0; k < D; k++) s += src[k] * f1w[k * TT + j];
        hid[r][j] = fmaxf(s, 0.f);
    }
    __syncthreads();
    // t = hid @ ft2 + b2
    for (int idx = tid; idx < 45 * TT; idx += 256) {
        int r = idx >> 6, j = idx & 63;
        float o = f2b[j];
#pragma unroll 4
        for (int k = 0; k < TT; k++) o += hid[r][k] * f2w[k * TT + j];
        if (r < NQQ) tq[r][j] = o;
        else tc[r - NQQ][j] = o;
    }
    __syncthreads();
    // la = 10 * tq @ tc^T  (rows q>=15 are zero: tq masked rows)
    for (int e = tid; e < NCC * NCC; e += 256) {
        int q = e / NCC, c = e % NCC;
        float s = 0.f;
        if (q < NQQ) {
#pragma unroll 4
            for (int k = 0; k < TT; k++) s += tq[q][k] * tc[c][k];
            s *= 10.0f;
        }
        la[q][c] = s;
    }
    __syncthreads();
    // Sinkhorn: 8-lane group per row/col; lane k8 covers 4 elements
    int grp = tid >> 3, k8 = tid & 7;
    for (int it = 0; it < SKI; ++it) {
        if (grp < NCC) {  // row lse
            float v[4], m = -INFINITY;
#pragma unroll
            for (int t = 0; t < 4; t++) {
                int c = k8 * 4 + t;
                v[t] = (c < NCC) ? la[grp][c] : -INFINITY;
                m = fmaxf(m, v[t]);
            }
            m = fmaxf(m, __shfl_xor(m, 1));
            m = fmaxf(m, __shfl_xor(m, 2));
            m = fmaxf(m, __shfl_xor(m, 4));
            float s = 0.f;
#pragma unroll
            for (int t = 0; t < 4; t++)
                if (k8 * 4 + t < NCC) s += __expf(v[t] - m);
            s += __shfl_xor(s, 1);
            s += __shfl_xor(s, 2);
            s += __shfl_xor(s, 4);
            float lse = m + __logf(s);
#pragma unroll
            for (int t = 0; t < 4; t++) {
                int c = k8 * 4 + t;
                if (c < NCC) la[grp][c] = v[t] - lse;
            }
        }
        __syncthreads();
        if (grp < NCC) {  // col lse
            float v[4], m = -INFINITY;
#pragma unroll
            for (int t = 0; t < 4; t++) {
                int q = k8 * 4 + t;
                v[t] = (q < NCC) ? la[q][grp] : -INFINITY;
                m = fmaxf(m, v[t]);
            }
            m = fmaxf(m, __shfl_xor(m, 1));
            m = fmaxf(m, __shfl_xor(m, 2));
            m = fmaxf(m, __shfl_xor(m, 4));
            float s = 0.f;
#pragma unroll
            for (int t = 0; t < 4; t++)
                if (k8 * 4 + t < NCC) s += __expf(v[t] - m);
            s += __shfl_xor(s, 1);
            s += __shfl_xor(s, 2);
            s += __shfl_xor(s, 4);
            float lse = m + __logf(s);
#pragma unroll
            for (int t = 0; t < 4; t++) {
                int q = k8 * 4 + t;
                if (q < NCC) la[q][grp] = v[t] - lse;
            }
        }
        __syncthreads();
    }
    for (int e = tid; e < NCC * NCC; e += 256) {
        int q = e / NCC, c = e % NCC;
        la[q][c] = __expf(la[q][c]);
    }
    __syncthreads();
    // moved + score
    float part = 0.f;
    for (int idx = tid; idx < NCC * D; idx += 256) {
        int q = idx >> 7, d = idx & 127;
        float mv = 0.f;
#pragma unroll 5
        for (int c = 0; c < NCC; c++) mv += la[q][c] * ce[c][d];
        float qv = h[(size_t)(g * NPG + q) * D + d];
        part += fmaxf(qv - mv, 0.f);
    }
    red[tid] = part;
    __syncthreads();
    for (int s2 = 128; s2 > 0; s2 >>= 1) {
        if (tid < s2) red[tid] += red[tid + s2];
        __syncthreads();
    }
    if (tid == 0) out[g] = -red[0];
}

extern "C" void kernel_launch(void* const* d_in, const int* in_sizes, int n_in,
                              void* d_out, int out_size, void* d_ws, size_t ws_size,
                              hipStream_t stream) {
    const float* nf  = (const float*)d_in[0];
    const float* ef  = (const float*)d_in[1];
    const float* mfi = (const float*)d_in[2];
    const float* enw = (const float*)d_in[3];
    const float* enb = (const float*)d_in[4];
    const float* eew = (const float*)d_in[5];
    const float* eeb = (const float*)d_in[6];
    const float* mw1 = (const float*)d_in[7];
    const float* mb1 = (const float*)d_in[8];
    const float* mw2 = (const float*)d_in[9];
    const float* mb2 = (const float*)d_in[10];
    const float* uw1 = (const float*)d_in[11];
    const float* ub1 = (const float*)d_in[12];
    const float* uw2 = (const float*)d_in[13];
    const float* ub2 = (const float*)d_in[14];
    const float* f1w = (const float*)d_in[15];
    const float* f1b = (const float*)d_in[16];
    const float* f2w = (const float*)d_in[17];
    const float* f2b = (const float*)d_in[18];
    const int* fr = (const int*)d_in[19];
    const int* to = (const int*)d_in[20];
    float* out = (float*)d_out;

    // workspace layout
    char* base = (char*)d_ws;
    size_t off = 0;
    float* h = (float*)(base + off);                 off += (size_t)NN * D * 4;
    unsigned short* h_hi = (unsigned short*)(base + off); off += (size_t)NN * D * 2;
    unsigned short* h_lo = (unsigned short*)(base + off); off += (size_t)NN * D * 2;
    // H1c fp32 region; Ub hi/lo pair aliases it (phase-disjoint within an iteration)
    float* H1c = (float*)(base + off);
    unsigned short* Ub_hi = (unsigned short*)H1c;
    unsigned short* Ub_lo = Ub_hi + (size_t)NN * 256;
    off += (size_t)NCR * 512 * 4;
    float* agg0 = (float*)(base + off); off += (size_t)NN * D * 4;
    float* agg1 = (float*)(base + off); off += (size_t)NN * D * 4;
    unsigned short* w1th = (unsigned short*)(base + off); off += 65536 * 2;
    unsigned short* w1tl = (unsigned short*)(base + off); off += 65536 * 2;
    unsigned short* w2th = (unsigned short*)(base + off); off += 32768 * 2;
    unsigned short* w2tl = (unsigned short*)(base + off); off += 32768 * 2;
    unsigned short* uw1th = (unsigned short*)(base + off); off += 65536 * 2;
    unsigned short* uw1tl = (unsigned short*)(base + off); off += 65536 * 2;
    unsigned short* uw2th = (unsigned short*)(base + off); off += 32768 * 2;
    unsigned short* uw2tl = (unsigned short*)(base + off); off += 32768 * 2;
    float* uv = (float*)(base + off); off += 512 * 4;

    k_encode<<<(NN * D + 255) / 256, 256, 0, stream>>>(nf, enw, enb, h, h_hi, h_lo);
    k_prep_uv<<<1, 256, 0, stream>>>(eew, eeb, mw1, mb1, uv);
    k_prep_w<<<768, 256, 0, stream>>>(mw1, mw2, uw1, uw2, w1th, w1tl, w2th, w2tl,
                                      uw1th, uw1tl, uw2th, uw2tl);

    for (int it = 0; it < NPROP; ++it) {
        k_h1c_mf<<<dim3(NCR / 64, 8), 256, 0, stream>>>(h_hi, h_lo, w1th, w1tl, H1c);
        k_edge_mf<<<dim3(BATCH, 2), 256, 0, stream>>>(H1c, uv, fr, to, ef, mfi,
                                                      w2th, w2tl, mb2, agg0, agg1);
        k_upd1_mf<<<dim3(NN / 64, 4), 256, 0, stream>>>(agg0, agg1, h_hi, h_lo,
                                                        uw1th, uw1tl, ub1, Ub_hi, Ub_lo);
        k_upd2_mf<<<dim3(NN / 64, 2), 256, 0, stream>>>(Ub_hi, Ub_lo, uw2th, uw2tl,
                                                        ub2, h, h_hi, h_lo);
    }

    k_tail<<<BATCH, 256, 0, stream>>>(h, f1w, f1b, f2w, f2b, out);
}

// Round 7
// 582.751 us; speedup vs baseline: 1.0602x; 1.0602x over previous
//
#include <hip/hip_runtime.h>

#define NN 15360        // total nodes
#define NCR 11520       // compacted H1 rows: 45 per graph (q 0..14, c 30..59)
#define EPG 135         // active edges per graph, contiguous per graph
#define BATCH 256
#define D 128
#define TT 64
#define NPG 60
#define NCC 30
#define NQQ 15
#define NPROP 5
#define SKI 10

typedef __attribute__((ext_vector_type(8))) short bf16x8;
typedef __attribute__((ext_vector_type(4))) float f32x4;

__device__ __forceinline__ float bf2f(unsigned short u) {
    union { float f; unsigned int i; } t;
    t.i = ((unsigned int)u) << 16;
    return t.f;
}
__device__ __forceinline__ unsigned short f2bf(float f) {
    union { float f; unsigned int i; } t;
    t.f = f;
    unsigned int r = t.i + 0x7fffu + ((t.i >> 16) & 1u);
    return (unsigned short)(r >> 16);
}
// split v = hi + lo with |lo| <= 2^-9 |v|; residual after pair ~2^-18
__device__ __forceinline__ void split_bf(float v, unsigned short& hi, unsigned short& lo) {
    hi = f2bf(v);
    lo = f2bf(v - bf2f(hi));
}

// ---------------- node encode: h[i,d] = nf[i]*w[d]+b[d]; fp32 + split ----------------
__global__ void k_encode(const float* __restrict__ nf, const float* __restrict__ w,
                         const float* __restrict__ b, float* __restrict__ h,
                         unsigned short* __restrict__ h_hi, unsigned short* __restrict__ h_lo) {
    int idx = blockIdx.x * 256 + threadIdx.x;
    if (idx >= NN * D) return;
    int d = idx & (D - 1);
    int i = idx >> 7;
    float v = nf[i] * w[d] + b[d];
    h[idx] = v;
    unsigned short hi, lo;
    split_bf(v, hi, lo);
    h_hi[idx] = hi;
    h_lo[idx] = lo;
}

// ---------------- edge-constant precompute: uv (512 fp32) ----------------
__global__ void k_prep_uv(const float* __restrict__ ew, const float* __restrict__ eb,
                          const float* __restrict__ w1, const float* __restrict__ b1,
                          float* __restrict__ uv) {
    int t = threadIdx.x;  // 0..255
    float u = 0.f, v = 0.f;
    for (int d = 0; d < D; ++d) {
        float wv = w1[(256 + d) * 256 + t];
        u += ew[d] * wv;
        v += eb[d] * wv;
    }
    uv[t] = u;
    uv[256 + t] = v + b1[t];
}

// ---------------- weight prep: transpose to [n][k], split into hi/lo bf16 -----------
__global__ void k_prep_w(const float* __restrict__ mw1, const float* __restrict__ mw2,
                         const float* __restrict__ uw1, const float* __restrict__ uw2,
                         unsigned short* __restrict__ w1th, unsigned short* __restrict__ w1tl,
                         unsigned short* __restrict__ w2th, unsigned short* __restrict__ w2tl,
                         unsigned short* __restrict__ uw1th, unsigned short* __restrict__ uw1tl,
                         unsigned short* __restrict__ uw2th, unsigned short* __restrict__ uw2tl) {
    int idx = blockIdx.x * 256 + threadIdx.x;
    float v;
    unsigned short *ph, *pl;
    int o;
    if (idx < 65536) {  // w1t [512][128]
        int n = idx >> 7, k = idx & 127;
        v = (n < 256) ? mw1[k * 256 + n] : mw1[(128 + k) * 256 + (n - 256)];
        ph = w1th; pl = w1tl; o = idx;
    } else if (idx < 98304) {  // w2t [128][256]
        o = idx - 65536;
        int n = o >> 8, k = o & 255;
        v = mw2[k * 128 + n];
        ph = w2th; pl = w2tl;
    } else if (idx < 163840) {  // uw1t [256][256]
        o = idx - 98304;
        int n = o >> 8, k = o & 255;
        v = uw1[k * 256 + n];
        ph = uw1th; pl = uw1tl;
    } else if (idx < 196608) {  // uw2t [128][256]
        o = idx - 163840;
        int n = o >> 8, k = o & 255;
        v = uw2[k * 128 + n];
        ph = uw2th; pl = uw2tl;
    } else {
        return;
    }
    unsigned short hi, lo;
    split_bf(v, hi, lo);
    ph[o] = hi;
    pl[o] = lo;
}

// ===== dense split-MFMA GEMMs: BM=64, BN=64, BK=64, 4 waves (2x2), 3-term =====
// A in LDS (row stride 72 ushorts, conflict-free b128); B fragments straight from
// global (weights are L2-resident and shared by all blocks).

// ---- H1c(11520 x 512) fp32 = gather(h) @ w1t^T ----
__global__ __launch_bounds__(256) void k_h1c_mf(const unsigned short* __restrict__ h_hi,
                                                const unsigned short* __restrict__ h_lo,
                                                const unsigned short* __restrict__ w1th,
                                                const unsigned short* __restrict__ w1tl,
                                                float* __restrict__ H1c) {
    __shared__ unsigned short AsH[64 * 72], AsL[64 * 72];
    __shared__ int rowNode[64];
    int m0 = blockIdx.x * 64, n0 = blockIdx.y * 64;
    int tid = threadIdx.x;
    int lane = tid & 63, wid = tid >> 6;
    int wr = wid >> 1, wc = wid & 1;
    if (tid < 64) {
        int m = m0 + tid;
        int g = m / 45;
        int p = m - g * 45;
        rowNode[tid] = g * 60 + (p < 15 ? p : p + 15);
    }
    f32x4 acc[2][2] = {};
    for (int k0 = 0; k0 < 128; k0 += 64) {
        __syncthreads();
        for (int c = tid; c < 512; c += 256) {
            int row = c >> 3, kc = c & 7;
            size_t asrc = (size_t)rowNode[row] * D + k0 + kc * 8;
            *(uint4*)&AsH[row * 72 + kc * 8] = *(const uint4*)&h_hi[asrc];
            *(uint4*)&AsL[row * 72 + kc * 8] = *(const uint4*)&h_lo[asrc];
        }
        __syncthreads();
#pragma unroll
        for (int kk = 0; kk < 2; ++kk) {
            int koff = kk * 32 + (lane >> 4) * 8;
            bf16x8 ah[2], al[2], bh[2], bl[2];
#pragma unroll
            for (int i = 0; i < 2; i++) {
                int r = (wr * 32 + i * 16 + (lane & 15)) * 72 + koff;
                ah[i] = *(bf16x8*)&AsH[r];
                al[i] = *(bf16x8*)&AsL[r];
            }
#pragma unroll
            for (int j = 0; j < 2; j++) {
                size_t br = (size_t)(n0 + wc * 32 + j * 16 + (lane & 15)) * 128 + k0 + koff;
                bh[j] = *(const bf16x8*)&w1th[br];
                bl[j] = *(const bf16x8*)&w1tl[br];
            }
#pragma unroll
            for (int i = 0; i < 2; i++)
#pragma unroll
                for (int j = 0; j < 2; j++) {
                    acc[i][j] = __builtin_amdgcn_mfma_f32_16x16x32_bf16(ah[i], bh[j], acc[i][j], 0, 0, 0);
                    acc[i][j] = __builtin_amdgcn_mfma_f32_16x16x32_bf16(al[i], bh[j], acc[i][j], 0, 0, 0);
                    acc[i][j] = __builtin_amdgcn_mfma_f32_16x16x32_bf16(ah[i], bl[j], acc[i][j], 0, 0, 0);
                }
        }
    }
    int rloc = (lane >> 4) * 4;
#pragma unroll
    for (int i = 0; i < 2; i++)
#pragma unroll
        for (int j = 0; j < 2; j++) {
            int col = n0 + wc * 32 + j * 16 + (lane & 15);
#pragma unroll
            for (int r = 0; r < 4; r++) {
                int m = m0 + wr * 32 + i * 16 + rloc + r;
                H1c[(size_t)m * 512 + col] = acc[i][j][r];
            }
        }
}

// ---- U(15360 x 256) = relu([agg0+agg1 | h] @ uw1t^T + b1), split out ----
__global__ __launch_bounds__(256) void k_upd1_mf(const float* __restrict__ agg0,
                                                 const float* __restrict__ agg1,
                                                 const unsigned short* __restrict__ h_hi,
                                                 const unsigned short* __restrict__ h_lo,
                                                 const unsigned short* __restrict__ uw1th,
                                                 const unsigned short* __restrict__ uw1tl,
                                                 const float* __restrict__ b1,
                                                 unsigned short* __restrict__ Ub_hi,
                                                 unsigned short* __restrict__ Ub_lo) {
    __shared__ unsigned short AsH[64 * 72], AsL[64 * 72];
    int m0 = blockIdx.x * 64, n0 = blockIdx.y * 64;
    int tid = threadIdx.x;
    int lane = tid & 63, wid = tid >> 6;
    int wr = wid >> 1, wc = wid & 1;
    f32x4 acc[2][2] = {};
    for (int k0 = 0; k0 < 256; k0 += 64) {
        __syncthreads();
        if (k0 < 128) {
            for (int c = tid; c < 512; c += 256) {
                int row = c >> 3, kc = c & 7;
                size_t s = (size_t)(m0 + row) * D + k0 + kc * 8;
                float4 a0 = *(const float4*)&agg0[s];
                float4 a1 = *(const float4*)&agg0[s + 4];
                float4 c0 = *(const float4*)&agg1[s];
                float4 c1 = *(const float4*)&agg1[s + 4];
                float v[8] = {a0.x + c0.x, a0.y + c0.y, a0.z + c0.z, a0.w + c0.w,
                              a1.x + c1.x, a1.y + c1.y, a1.z + c1.z, a1.w + c1.w};
                unsigned int ph[4], pl[4];
#pragma unroll
                for (int t = 0; t < 4; t++) {
                    unsigned short h0, l0, h1, l1;
                    split_bf(v[2 * t], h0, l0);
                    split_bf(v[2 * t + 1], h1, l1);
                    ph[t] = (unsigned int)h0 | ((unsigned int)h1 << 16);
                    pl[t] = (unsigned int)l0 | ((unsigned int)l1 << 16);
                }
                *(uint4*)&AsH[row * 72 + kc * 8] = make_uint4(ph[0], ph[1], ph[2], ph[3]);
                *(uint4*)&AsL[row * 72 + kc * 8] = make_uint4(pl[0], pl[1], pl[2], pl[3]);
            }
        } else {
            for (int c = tid; c < 512; c += 256) {
                int row = c >> 3, kc = c & 7;
                size_t s = (size_t)(m0 + row) * D + (k0 - 128) + kc * 8;
                *(uint4*)&AsH[row * 72 + kc * 8] = *(const uint4*)&h_hi[s];
                *(uint4*)&AsL[row * 72 + kc * 8] = *(const uint4*)&h_lo[s];
            }
        }
        __syncthreads();
#pragma unroll
        for (int kk = 0; kk < 2; ++kk) {
            int koff = kk * 32 + (lane >> 4) * 8;
            bf16x8 ah[2], al[2], bh[2], bl[2];
#pragma unroll
            for (int i = 0; i < 2; i++) {
                int r = (wr * 32 + i * 16 + (lane & 15)) * 72 + koff;
                ah[i] = *(bf16x8*)&AsH[r];
                al[i] = *(bf16x8*)&AsL[r];
            }
#pragma unroll
            for (int j = 0; j < 2; j++) {
                size_t br = (size_t)(n0 + wc * 32 + j * 16 + (lane & 15)) * 256 + k0 + koff;
                bh[j] = *(const bf16x8*)&uw1th[br];
                bl[j] = *(const bf16x8*)&uw1tl[br];
            }
#pragma unroll
            for (int i = 0; i < 2; i++)
#pragma unroll
                for (int j = 0; j < 2; j++) {
                    acc[i][j] = __builtin_amdgcn_mfma_f32_16x16x32_bf16(ah[i], bh[j], acc[i][j], 0, 0, 0);
                    acc[i][j] = __builtin_amdgcn_mfma_f32_16x16x32_bf16(al[i], bh[j], acc[i][j], 0, 0, 0);
                    acc[i][j] = __builtin_amdgcn_mfma_f32_16x16x32_bf16(ah[i], bl[j], acc[i][j], 0, 0, 0);
                }
        }
    }
    int rloc = (lane >> 4) * 4;
#pragma unroll
    for (int i = 0; i < 2; i++)
#pragma unroll
        for (int j = 0; j < 2; j++) {
            int col = n0 + wc * 32 + j * 16 + (lane & 15);
            float bias = b1[col];
#pragma unroll
            for (int r = 0; r < 4; r++) {
                int m = m0 + wr * 32 + i * 16 + rloc + r;
                float v = fmaxf(acc[i][j][r] + bias, 0.f);
                unsigned short hi, lo;
                split_bf(v, hi, lo);
                Ub_hi[(size_t)m * 256 + col] = hi;
                Ub_lo[(size_t)m * 256 + col] = lo;
            }
        }
}

// ---- h(15360x128) += U @ uw2t^T + b2 ; fp32 residual + re-split h ----
__global__ __launch_bounds__(256) void k_upd2_mf(const unsigned short* __restrict__ Ub_hi,
                                                 const unsigned short* __restrict__ Ub_lo,
                                                 const unsigned short* __restrict__ uw2th,
                                                 const unsigned short* __restrict__ uw2tl,
                                                 const float* __restrict__ b2,
                                                 float* __restrict__ h,
                                                 unsigned short* __restrict__ h_hi,
                                                 unsigned short* __restrict__ h_lo) {
    __shared__ unsigned short AsH[64 * 72], AsL[64 * 72];
    int m0 = blockIdx.x * 64, n0 = blockIdx.y * 64;
    int tid = threadIdx.x;
    int lane = tid & 63, wid = tid >> 6;
    int wr = wid >> 1, wc = wid & 1;
    f32x4 acc[2][2] = {};
    for (int k0 = 0; k0 < 256; k0 += 64) {
        __syncthreads();
        for (int c = tid; c < 512; c += 256) {
            int row = c >> 3, kc = c & 7;
            size_t s = (size_t)(m0 + row) * 256 + k0 + kc * 8;
            *(uint4*)&AsH[row * 72 + kc * 8] = *(const uint4*)&Ub_hi[s];
            *(uint4*)&AsL[row * 72 + kc * 8] = *(const uint4*)&Ub_lo[s];
        }
        __syncthreads();
#pragma unroll
        for (int kk = 0; kk < 2; ++kk) {
            int koff = kk * 32 + (lane >> 4) * 8;
            bf16x8 ah[2], al[2], bh[2], bl[2];
#pragma unroll
            for (int i = 0; i < 2; i++) {
                int r = (wr * 32 + i * 16 + (lane & 15)) * 72 + koff;
                ah[i] = *(bf16x8*)&AsH[r];
                al[i] = *(bf16x8*)&AsL[r];
            }
#pragma unroll
            for (int j = 0; j < 2; j++) {
                size_t br = (size_t)(n0 + wc * 32 + j * 16 + (lane & 15)) * 256 + k0 + koff;
                bh[j] = *(const bf16x8*)&uw2th[br];
                bl[j] = *(const bf16x8*)&uw2tl[br];
            }
#pragma unroll
            for (int i = 0; i < 2; i++)
#pragma unroll
                for (int j = 0; j < 2; j++) {
                    acc[i][j] = __builtin_amdgcn_mfma_f32_16x16x32_bf16(ah[i], bh[j], acc[i][j], 0, 0, 0);
                    acc[i][j] = __builtin_amdgcn_mfma_f32_16x16x32_bf16(al[i], bh[j], acc[i][j], 0, 0, 0);
                    acc[i][j] = __builtin_amdgcn_mfma_f32_16x16x32_bf16(ah[i], bl[j], acc[i][j], 0, 0, 0);
                }
        }
    }
    int rloc = (lane >> 4) * 4;
#pragma unroll
    for (int i = 0; i < 2; i++)
#pragma unroll
        for (int j = 0; j < 2; j++) {
            int col = n0 + wc * 32 + j * 16 + (lane & 15);
            float bias = b2[col];
#pragma unroll
            for (int r = 0; r < 4; r++) {
                int m = m0 + wr * 32 + i * 16 + rloc + r;
                size_t o = (size_t)m * D + col;
                float v = h[o] + acc[i][j][r] + bias;
                h[o] = v;
                unsigned short hi, lo;
                split_bf(v, hi, lo);
                h_hi[o] = hi;
                h_lo[o] = lo;
            }
        }
}

// ===== per-graph edge pass, split-MFMA, M-split: block=(graph, half) =====
__global__ __launch_bounds__(256) void k_edge_mf(const float* __restrict__ H1c,
                                                 const float* __restrict__ uv,
                                                 const int* __restrict__ fr,
                                                 const int* __restrict__ to,
                                                 const float* __restrict__ ef,
                                                 const float* __restrict__ mfi,
                                                 const unsigned short* __restrict__ w2th,
                                                 const unsigned short* __restrict__ w2tl,
                                                 const float* __restrict__ b2,
                                                 float* __restrict__ agg0,
                                                 float* __restrict__ agg1) {
    __shared__ unsigned short AsH[80 * 40], AsL[80 * 40];  // stride 80B (5x16B)
    __shared__ float aggl[NPG][128];
    __shared__ float uvl[512];
    __shared__ int cfs[80], ctc[80], ctl[80];
    __shared__ float efs[80], ms_[80];
    int g = blockIdx.x;
    int half = blockIdx.y;
    int tid = threadIdx.x;
    int lane = tid & 63, wid = tid >> 6;
    int cnt = half ? (EPG - 72) : 72;  // 63 or 72
    int ebase = g * EPG + half * 72;
    if (tid < 80) {
        if (tid < cnt) {
            int f = fr[ebase + tid] - g * 60;
            int t = to[ebase + tid] - g * 60;
            cfs[tid] = g * 45 + (f < 15 ? f : f - 15);
            ctc[tid] = g * 45 + (t < 15 ? t : t - 15);
            ctl[tid] = t;
            efs[tid] = ef[ebase + tid];
            ms_[tid] = mfi[ebase + tid];
        } else {
            cfs[tid] = g * 45; ctc[tid] = g * 45; ctl[tid] = 0;
            efs[tid] = 0.f; ms_[tid] = 0.f;
        }
    }
    for (int i = tid; i < 512; i += 256) uvl[i] = uv[i];
    for (int i = tid; i < NPG * 128; i += 256) (&aggl[0][0])[i] = 0.f;
    f32x4 acc[5][2] = {};
    for (int ks = 0; ks < 8; ++ks) {
        __syncthreads();
        for (int c = tid; c < 320; c += 256) {
            int row = c >> 2, kc = c & 3;
            int k = ks * 32 + kc * 8;
            const float* pf = H1c + (size_t)cfs[row] * 512 + k;
            const float* pt = H1c + (size_t)ctc[row] * 512 + 256 + k;
            float e_ = efs[row];
            float4 f0 = *(const float4*)pf, f1 = *(const float4*)(pf + 4);
            float4 t0 = *(const float4*)pt, t1 = *(const float4*)(pt + 4);
            float zf[8] = {f0.x + t0.x, f0.y + t0.y, f0.z + t0.z, f0.w + t0.w,
                           f1.x + t1.x, f1.y + t1.y, f1.z + t1.z, f1.w + t1.w};
            unsigned int ph[4], pl[4];
#pragma unroll
            for (int t = 0; t < 4; t++) {
                float z0 = fmaxf(zf[2 * t]     + e_ * uvl[k + 2 * t]     + uvl[256 + k + 2 * t], 0.f);
                float z1 = fmaxf(zf[2 * t + 1] + e_ * uvl[k + 2 * t + 1] + uvl[256 + k + 2 * t + 1], 0.f);
                unsigned short h0, l0, h1, l1;
                split_bf(z0, h0, l0);
                split_bf(z1, h1, l1);
                ph[t] = (unsigned int)h0 | ((unsigned int)h1 << 16);
                pl[t] = (unsigned int)l0 | ((unsigned int)l1 << 16);
            }
            *(uint4*)&AsH[row * 40 + kc * 8] = make_uint4(ph[0], ph[1], ph[2], ph[3]);
            *(uint4*)&AsL[row * 40 + kc * 8] = make_uint4(pl[0], pl[1], pl[2], pl[3]);
        }
        __syncthreads();
        int koff = (lane >> 4) * 8;
        bf16x8 bh[2], bl[2];
#pragma unroll
        for (int j = 0; j < 2; j++) {
            size_t br = (size_t)(wid * 32 + j * 16 + (lane & 15)) * 256 + ks * 32 + koff;
            bh[j] = *(const bf16x8*)&w2th[br];
            bl[j] = *(const bf16x8*)&w2tl[br];
        }
#pragma unroll
        for (int i = 0; i < 5; i++) {
            int r = (i * 16 + (lane & 15)) * 40 + koff;
            bf16x8 ah = *(bf16x8*)&AsH[r];
            bf16x8 al = *(bf16x8*)&AsL[r];
#pragma unroll
            for (int j = 0; j < 2; j++) {
                acc[i][j] = __builtin_amdgcn_mfma_f32_16x16x32_bf16(ah, bh[j], acc[i][j], 0, 0, 0);
                acc[i][j] = __builtin_amdgcn_mfma_f32_16x16x32_bf16(al, bh[j], acc[i][j], 0, 0, 0);
                acc[i][j] = __builtin_amdgcn_mfma_f32_16x16x32_bf16(ah, bl[j], acc[i][j], 0, 0, 0);
            }
        }
    }
    __syncthreads();
    int rloc = (lane >> 4) * 4;
#pragma unroll
    for (int i = 0; i < 5; i++)
#pragma unroll
        for (int j = 0; j < 2; j++) {
            int col = wid * 32 + j * 16 + (lane & 15);
            float bias = b2[col];
#pragma unroll
            for (int r = 0; r < 4; r++) {
                int e = i * 16 + rloc + r;
                if (e < cnt) {
                    float val = (acc[i][j][r] + bias) * ms_[e];
                    atomicAdd(&aggl[ctl[e]][col], val);
                }
            }
        }
    __syncthreads();
    float* dst = half ? agg1 : agg0;
    for (int idx = tid; idx < NPG * 128; idx += 256) {
        int r = idx >> 7, c = idx & 127;
        dst[(size_t)(g * NPG + r) * D + c] = aggl[r][c];
    }
}

// ---------------- final transform, 45 useful rows per graph -----------------
// block b -> graph g = b/45, p = b%45; p<15: q row p; else c row p-15 (node +30).
__global__ __launch_bounds__(64) void k_transform2(const float* __restrict__ h,
                                                   const float* __restrict__ w1,
                                                   const float* __restrict__ b1,
                                                   const float* __restrict__ w2,
                                                   const float* __restrict__ b2,
                                                   float* __restrict__ tall) {
    __shared__ float row[D];
    __shared__ float hid[TT];
    int b = blockIdx.x;
    int g = b / 45, p = b - g * 45;
    int node = g * NPG + (p < NQQ ? p : p + 15);
    int j = threadIdx.x;  // 0..63
    row[j] = h[(size_t)node * D + j];
    row[j + 64] = h[(size_t)node * D + j + 64];
    __syncthreads();
    float s = b1[j];
    for (int k = 0; k < D; k++) s += row[k] * w1[k * TT + j];
    hid[j] = fmaxf(s, 0.f);
    __syncthreads();
    float o = b2[j];
    for (int k = 0; k < TT; k++) o += hid[k] * w2[k * TT + j];
    tall[(size_t)b * TT + j] = o;
}

// ===== per-graph Sinkhorn + score; wave-parallel lse, padded LDS =====
__global__ __launch_bounds__(256) void k_sinkhorn2(const float* __restrict__ h,
                                                   const float* __restrict__ tall,
                                                   float* __restrict__ out) {
    __shared__ float ce[NCC][D];
    __shared__ float tq[NQQ][TT + 2];
    __shared__ float tc[NCC][TT + 2];
    __shared__ float la[NCC][33];    // pad 33 -> conflict-free rows AND cols
    __shared__ float red[256];
    int g = blockIdx.x;
    int tid = threadIdx.x;
    for (int idx = tid; idx < NCC * D; idx += 256) {
        int c = idx >> 7, d = idx & 127;
        ce[c][d] = h[(size_t)(g * NPG + NCC + c) * D + d];
    }
    for (int idx = tid; idx < 45 * TT; idx += 256) {
        int r = idx >> 6, j = idx & 63;
        float v = tall[(size_t)(g * 45 + r) * TT + j];
        if (r < NQQ) tq[r][j] = v;
        else tc[r - NQQ][j] = v;
    }
    __syncthreads();
    // la = 10 * tq @ tc^T ; q rows >= 15 are masked to zero
    for (int e = tid; e < NCC * NCC; e += 256) {
        int q = e / NCC, c = e % NCC;
        float s = 0.f;
        if (q < NQQ) {
#pragma unroll 4
            for (int k = 0; k < TT; k++) s += tq[q][k] * tc[c][k];
            s *= 10.0f;
        }
        la[q][c] = s;
    }
    __syncthreads();
    int grp = tid >> 3, k8 = tid & 7;  // 8-lane group per row/col
    for (int it = 0; it < SKI; ++it) {
        if (grp < NCC) {  // row lse
            float v[4], m = -INFINITY;
#pragma unroll
            for (int t = 0; t < 4; t++) {
                int c = k8 * 4 + t;
                v[t] = (c < NCC) ? la[grp][c] : -INFINITY;
                m = fmaxf(m, v[t]);
            }
            m = fmaxf(m, __shfl_xor(m, 1));
            m = fmaxf(m, __shfl_xor(m, 2));
            m = fmaxf(m, __shfl_xor(m, 4));
            float s = 0.f;
#pragma unroll
            for (int t = 0; t < 4; t++)
                if (k8 * 4 + t < NCC) s += __expf(v[t] - m);
            s += __shfl_xor(s, 1);
            s += __shfl_xor(s, 2);
            s += __shfl_xor(s, 4);
            float lse = m + __logf(s);
#pragma unroll
            for (int t = 0; t < 4; t++) {
                int c = k8 * 4 + t;
                if (c < NCC) la[grp][c] = v[t] - lse;
            }
        }
        __syncthreads();
        if (grp < NCC) {  // col lse
            float v[4], m = -INFINITY;
#pragma unroll
            for (int t = 0; t < 4; t++) {
                int q = k8 * 4 + t;
                v[t] = (q < NCC) ? la[q][grp] : -INFINITY;
                m = fmaxf(m, v[t]);
            }
            m = fmaxf(m, __shfl_xor(m, 1));
            m = fmaxf(m, __shfl_xor(m, 2));
            m = fmaxf(m, __shfl_xor(m, 4));
            float s = 0.f;
#pragma unroll
            for (int t = 0; t < 4; t++)
                if (k8 * 4 + t < NCC) s += __expf(v[t] - m);
            s += __shfl_xor(s, 1);
            s += __shfl_xor(s, 2);
            s += __shfl_xor(s, 4);
            float lse = m + __logf(s);
#pragma unroll
            for (int t = 0; t < 4; t++) {
                int q = k8 * 4 + t;
                if (q < NCC) la[q][grp] = v[t] - lse;
            }
        }
        __syncthreads();
    }
    for (int e = tid; e < NCC * NCC; e += 256) {
        int q = e / NCC, c = e % NCC;
        la[q][c] = __expf(la[q][c]);
    }
    __syncthreads();
    float part = 0.f;
    for (int idx = tid; idx < NCC * D; idx += 256) {
        int q = idx >> 7, d = idx & 127;
        float mv = 0.f;
#pragma unroll 5
        for (int c = 0; c < NCC; c++) mv += la[q][c] * ce[c][d];
        float qv = h[(size_t)(g * NPG + q) * D + d];
        part += fmaxf(qv - mv, 0.f);
    }
    red[tid] = part;
    __syncthreads();
    for (int s2 = 128; s2 > 0; s2 >>= 1) {
        if (tid < s2) red[tid] += red[tid + s2];
        __syncthreads();
    }
    if (tid == 0) out[g] = -red[0];
}

extern "C" void kernel_launch(void* const* d_in, const int* in_sizes, int n_in,
                              void* d_out, int out_size, void* d_ws, size_t ws_size,
                              hipStream_t stream) {
    const float* nf  = (const float*)d_in[0];
    const float* ef  = (const float*)d_in[1];
    const float* mfi = (const float*)d_in[2];
    const float* enw = (const float*)d_in[3];
    const float* enb = (const float*)d_in[4];
    const float* eew = (const float*)d_in[5];
    const float* eeb = (const float*)d_in[6];
    const float* mw1 = (const float*)d_in[7];
    const float* mb1 = (const float*)d_in[8];
    const float* mw2 = (const float*)d_in[9];
    const float* mb2 = (const float*)d_in[10];
    const float* uw1 = (const float*)d_in[11];
    const float* ub1 = (const float*)d_in[12];
    const float* uw2 = (const float*)d_in[13];
    const float* ub2 = (const float*)d_in[14];
    const float* f1w = (const float*)d_in[15];
    const float* f1b = (const float*)d_in[16];
    const float* f2w = (const float*)d_in[17];
    const float* f2b = (const float*)d_in[18];
    const int* fr = (const int*)d_in[19];
    const int* to = (const int*)d_in[20];
    float* out = (float*)d_out;

    // workspace layout
    char* base = (char*)d_ws;
    size_t off = 0;
    float* h = (float*)(base + off);                 off += (size_t)NN * D * 4;
    unsigned short* h_hi = (unsigned short*)(base + off); off += (size_t)NN * D * 2;
    unsigned short* h_lo = (unsigned short*)(base + off); off += (size_t)NN * D * 2;
    // H1c fp32 region; Ub hi/lo pair aliases it (phase-disjoint within an iteration)
    float* H1c = (float*)(base + off);
    unsigned short* Ub_hi = (unsigned short*)H1c;
    unsigned short* Ub_lo = Ub_hi + (size_t)NN * 256;
    off += (size_t)NCR * 512 * 4;
    float* agg0 = (float*)(base + off); off += (size_t)NN * D * 4;
    float* agg1 = (float*)(base + off); off += (size_t)NN * D * 4;
    unsigned short* w1th = (unsigned short*)(base + off); off += 65536 * 2;
    unsigned short* w1tl = (unsigned short*)(base + off); off += 65536 * 2;
    unsigned short* w2th = (unsigned short*)(base + off); off += 32768 * 2;
    unsigned short* w2tl = (unsigned short*)(base + off); off += 32768 * 2;
    unsigned short* uw1th = (unsigned short*)(base + off); off += 65536 * 2;
    unsigned short* uw1tl = (unsigned short*)(base + off); off += 65536 * 2;
    unsigned short* uw2th = (unsigned short*)(base + off); off += 32768 * 2;
    unsigned short* uw2tl = (unsigned short*)(base + off); off += 32768 * 2;
    float* uv = (float*)(base + off); off += 512 * 4;
    float* tall = (float*)agg0;  // alias: tail runs after the loop, agg dead (11520*64 f32 fits)

    k_encode<<<(NN * D + 255) / 256, 256, 0, stream>>>(nf, enw, enb, h, h_hi, h_lo);
    k_prep_uv<<<1, 256, 0, stream>>>(eew, eeb, mw1, mb1, uv);
    k_prep_w<<<768, 256, 0, stream>>>(mw1, mw2, uw1, uw2, w1th, w1tl, w2th, w2tl,
                                      uw1th, uw1tl, uw2th, uw2tl);

    for (int it = 0; it < NPROP; ++it) {
        k_h1c_mf<<<dim3(NCR / 64, 8), 256, 0, stream>>>(h_hi, h_lo, w1th, w1tl, H1c);
        k_edge_mf<<<dim3(BATCH, 2), 256, 0, stream>>>(H1c, uv, fr, to, ef, mfi,
                                                      w2th, w2tl, mb2, agg0, agg1);
        k_upd1_mf<<<dim3(NN / 64, 4), 256, 0, stream>>>(agg0, agg1, h_hi, h_lo,
                                                        uw1th, uw1tl, ub1, Ub_hi, Ub_lo);
        k_upd2_mf<<<dim3(NN / 64, 2), 256, 0, stream>>>(Ub_hi, Ub_lo, uw2th, uw2tl,
                                                        ub2, h, h_hi, h_lo);
    }

    k_transform2<<<NCR, 64, 0, stream>>>(h, f1w, f1b, f2w, f2b, tall);
    k_sinkhorn2<<<BATCH, 256, 0, stream>>>(h, tall, out);
}

// Round 8
// 482.527 us; speedup vs baseline: 1.2805x; 1.2077x over previous
//
#include <hip/hip_runtime.h>

#define NN 15360        // total nodes
#define NCR 11520       // compacted H1 rows: 45 per graph (q 0..14, c 30..59)
#define EPG 135         // active edges per graph: [45 q-edges][90 c-edges]
#define BATCH 256
#define D 128
#define TT 64
#define NPG 60
#define NCC 30
#define NQQ 15
#define NPROP 5
#define SKI 10

typedef __attribute__((ext_vector_type(8))) short bf16x8;
typedef __attribute__((ext_vector_type(4))) float f32x4;

__device__ __forceinline__ float bf2f(unsigned short u) {
    union { float f; unsigned int i; } t;
    t.i = ((unsigned int)u) << 16;
    return t.f;
}
__device__ __forceinline__ unsigned short f2bf(float f) {
    union { float f; unsigned int i; } t;
    t.f = f;
    unsigned int r = t.i + 0x7fffu + ((t.i >> 16) & 1u);
    return (unsigned short)(r >> 16);
}
// split v = hi + lo with |lo| <= 2^-9 |v|; residual after pair ~2^-18
__device__ __forceinline__ void split_bf(float v, unsigned short& hi, unsigned short& lo) {
    hi = f2bf(v);
    lo = f2bf(v - bf2f(hi));
}

// ---------------- node encode: h[i,d] = nf[i]*w[d]+b[d]; fp32 + split ----------------
__global__ void k_encode(const float* __restrict__ nf, const float* __restrict__ w,
                         const float* __restrict__ b, float* __restrict__ h,
                         unsigned short* __restrict__ h_hi, unsigned short* __restrict__ h_lo) {
    int idx = blockIdx.x * 256 + threadIdx.x;
    if (idx >= NN * D) return;
    int d = idx & (D - 1);
    int i = idx >> 7;
    float v = nf[i] * w[d] + b[d];
    h[idx] = v;
    unsigned short hi, lo;
    split_bf(v, hi, lo);
    h_hi[idx] = hi;
    h_lo[idx] = lo;
}

// ---------------- edge-constant precompute: uv (512 fp32) ----------------
__global__ void k_prep_uv(const float* __restrict__ ew, const float* __restrict__ eb,
                          const float* __restrict__ w1, const float* __restrict__ b1,
                          float* __restrict__ uv) {
    int t = threadIdx.x;  // 0..255
    float u = 0.f, v = 0.f;
    for (int d = 0; d < D; ++d) {
        float wv = w1[(256 + d) * 256 + t];
        u += ew[d] * wv;
        v += eb[d] * wv;
    }
    uv[t] = u;
    uv[256 + t] = v + b1[t];
}

// ---------------- weight prep: transpose to [n][k], split into hi/lo bf16 -----------
__global__ void k_prep_w(const float* __restrict__ mw1, const float* __restrict__ mw2,
                         const float* __restrict__ uw1, const float* __restrict__ uw2,
                         unsigned short* __restrict__ w1th, unsigned short* __restrict__ w1tl,
                         unsigned short* __restrict__ w2th, unsigned short* __restrict__ w2tl,
                         unsigned short* __restrict__ uw1th, unsigned short* __restrict__ uw1tl,
                         unsigned short* __restrict__ uw2th, unsigned short* __restrict__ uw2tl) {
    int idx = blockIdx.x * 256 + threadIdx.x;
    float v;
    unsigned short *ph, *pl;
    int o;
    if (idx < 65536) {  // w1t [512][128]
        int n = idx >> 7, k = idx & 127;
        v = (n < 256) ? mw1[k * 256 + n] : mw1[(128 + k) * 256 + (n - 256)];
        ph = w1th; pl = w1tl; o = idx;
    } else if (idx < 98304) {  // w2t [128][256]
        o = idx - 65536;
        int n = o >> 8, k = o & 255;
        v = mw2[k * 128 + n];
        ph = w2th; pl = w2tl;
    } else if (idx < 163840) {  // uw1t [256][256]
        o = idx - 98304;
        int n = o >> 8, k = o & 255;
        v = uw1[k * 256 + n];
        ph = uw1th; pl = uw1tl;
    } else if (idx < 196608) {  // uw2t [128][256]
        o = idx - 163840;
        int n = o >> 8, k = o & 255;
        v = uw2[k * 128 + n];
        ph = uw2th; pl = uw2tl;
    } else {
        return;
    }
    unsigned short hi, lo;
    split_bf(v, hi, lo);
    ph[o] = hi;
    pl[o] = lo;
}

// ===== dense split-MFMA GEMMs, A+B LDS-staged (stride 72 = conflict-free b128) =====

// ---- H1c(11520 x 512) fp32 = gather(h) @ w1t^T ; BM=64 BN=64 BK=64, 4 waves ----
__global__ __launch_bounds__(256) void k_h1c_mf(const unsigned short* __restrict__ h_hi,
                                                const unsigned short* __restrict__ h_lo,
                                                const unsigned short* __restrict__ w1th,
                                                const unsigned short* __restrict__ w1tl,
                                                float* __restrict__ H1c) {
    __shared__ unsigned short AsH[64 * 72], AsL[64 * 72];
    __shared__ unsigned short BsH[64 * 72], BsL[64 * 72];
    __shared__ int rowNode[64];
    int m0 = blockIdx.x * 64, n0 = blockIdx.y * 64;
    int tid = threadIdx.x;
    int lane = tid & 63, wid = tid >> 6;
    int wr = wid >> 1, wc = wid & 1;
    if (tid < 64) {
        int m = m0 + tid;
        int g = m / 45;
        int p = m - g * 45;
        rowNode[tid] = g * 60 + (p < 15 ? p : p + 15);
    }
    f32x4 acc[2][2] = {};
    for (int k0 = 0; k0 < 128; k0 += 64) {
        __syncthreads();
        for (int c = tid; c < 512; c += 256) {
            int row = c >> 3, kc = c & 7;
            size_t asrc = (size_t)rowNode[row] * D + k0 + kc * 8;
            *(uint4*)&AsH[row * 72 + kc * 8] = *(const uint4*)&h_hi[asrc];
            *(uint4*)&AsL[row * 72 + kc * 8] = *(const uint4*)&h_lo[asrc];
            size_t bsrc = (size_t)(n0 + row) * 128 + k0 + kc * 8;
            *(uint4*)&BsH[row * 72 + kc * 8] = *(const uint4*)&w1th[bsrc];
            *(uint4*)&BsL[row * 72 + kc * 8] = *(const uint4*)&w1tl[bsrc];
        }
        __syncthreads();
#pragma unroll
        for (int kk = 0; kk < 2; ++kk) {
            int koff = kk * 32 + (lane >> 4) * 8;
            bf16x8 ah[2], al[2], bh[2], bl[2];
#pragma unroll
            for (int i = 0; i < 2; i++) {
                int r = (wr * 32 + i * 16 + (lane & 15)) * 72 + koff;
                ah[i] = *(bf16x8*)&AsH[r];
                al[i] = *(bf16x8*)&AsL[r];
            }
#pragma unroll
            for (int j = 0; j < 2; j++) {
                int r = (wc * 32 + j * 16 + (lane & 15)) * 72 + koff;
                bh[j] = *(bf16x8*)&BsH[r];
                bl[j] = *(bf16x8*)&BsL[r];
            }
#pragma unroll
            for (int i = 0; i < 2; i++)
#pragma unroll
                for (int j = 0; j < 2; j++) {
                    acc[i][j] = __builtin_amdgcn_mfma_f32_16x16x32_bf16(ah[i], bh[j], acc[i][j], 0, 0, 0);
                    acc[i][j] = __builtin_amdgcn_mfma_f32_16x16x32_bf16(al[i], bh[j], acc[i][j], 0, 0, 0);
                    acc[i][j] = __builtin_amdgcn_mfma_f32_16x16x32_bf16(ah[i], bl[j], acc[i][j], 0, 0, 0);
                }
        }
    }
    int rloc = (lane >> 4) * 4;
#pragma unroll
    for (int i = 0; i < 2; i++)
#pragma unroll
        for (int j = 0; j < 2; j++) {
            int col = n0 + wc * 32 + j * 16 + (lane & 15);
#pragma unroll
            for (int r = 0; r < 4; r++) {
                int m = m0 + wr * 32 + i * 16 + rloc + r;
                H1c[(size_t)m * 512 + col] = acc[i][j][r];
            }
        }
}

// ---- U(15360 x 256) = relu([agg | h] @ uw1t^T + b1); agg = {aggQ | 0 | aggC0+aggC1} ----
__global__ __launch_bounds__(256) void k_upd1_mf(const float* __restrict__ aggQ,
                                                 const float* __restrict__ aggC0,
                                                 const float* __restrict__ aggC1,
                                                 const unsigned short* __restrict__ h_hi,
                                                 const unsigned short* __restrict__ h_lo,
                                                 const unsigned short* __restrict__ uw1th,
                                                 const unsigned short* __restrict__ uw1tl,
                                                 const float* __restrict__ b1,
                                                 unsigned short* __restrict__ Ub_hi,
                                                 unsigned short* __restrict__ Ub_lo) {
    __shared__ unsigned short AsH[64 * 72], AsL[64 * 72];
    __shared__ unsigned short BsH[64 * 72], BsL[64 * 72];
    int m0 = blockIdx.x * 64, n0 = blockIdx.y * 64;
    int tid = threadIdx.x;
    int lane = tid & 63, wid = tid >> 6;
    int wr = wid >> 1, wc = wid & 1;
    f32x4 acc[2][2] = {};
    for (int k0 = 0; k0 < 256; k0 += 64) {
        __syncthreads();
        if (k0 < 128) {
            for (int c = tid; c < 512; c += 256) {
                int row = c >> 3, kc = c & 7;
                int n = m0 + row;
                int g = n / 60, p = n - g * 60;
                int k = k0 + kc * 8;
                float v[8];
                if (p < NQQ) {
                    const float* s = aggQ + ((size_t)(g * NQQ + p)) * D + k;
                    float4 a0 = *(const float4*)s, a1 = *(const float4*)(s + 4);
                    v[0]=a0.x; v[1]=a0.y; v[2]=a0.z; v[3]=a0.w;
                    v[4]=a1.x; v[5]=a1.y; v[6]=a1.z; v[7]=a1.w;
                } else if (p < NCC) {
#pragma unroll
                    for (int t = 0; t < 8; t++) v[t] = 0.f;
                } else {
                    size_t s = ((size_t)(g * NCC + p - NCC)) * D + k;
                    float4 a0 = *(const float4*)&aggC0[s], a1 = *(const float4*)&aggC0[s + 4];
                    float4 c0 = *(const float4*)&aggC1[s], c1 = *(const float4*)&aggC1[s + 4];
                    v[0]=a0.x+c0.x; v[1]=a0.y+c0.y; v[2]=a0.z+c0.z; v[3]=a0.w+c0.w;
                    v[4]=a1.x+c1.x; v[5]=a1.y+c1.y; v[6]=a1.z+c1.z; v[7]=a1.w+c1.w;
                }
                unsigned int ph[4], pl[4];
#pragma unroll
                for (int t = 0; t < 4; t++) {
                    unsigned short h0, l0, h1, l1;
                    split_bf(v[2 * t], h0, l0);
                    split_bf(v[2 * t + 1], h1, l1);
                    ph[t] = (unsigned int)h0 | ((unsigned int)h1 << 16);
                    pl[t] = (unsigned int)l0 | ((unsigned int)l1 << 16);
                }
                *(uint4*)&AsH[row * 72 + kc * 8] = make_uint4(ph[0], ph[1], ph[2], ph[3]);
                *(uint4*)&AsL[row * 72 + kc * 8] = make_uint4(pl[0], pl[1], pl[2], pl[3]);
            }
        } else {
            for (int c = tid; c < 512; c += 256) {
                int row = c >> 3, kc = c & 7;
                size_t s = (size_t)(m0 + row) * D + (k0 - 128) + kc * 8;
                *(uint4*)&AsH[row * 72 + kc * 8] = *(const uint4*)&h_hi[s];
                *(uint4*)&AsL[row * 72 + kc * 8] = *(const uint4*)&h_lo[s];
            }
        }
        for (int c = tid; c < 512; c += 256) {
            int row = c >> 3, kc = c & 7;
            size_t bsrc = (size_t)(n0 + row) * 256 + k0 + kc * 8;
            *(uint4*)&BsH[row * 72 + kc * 8] = *(const uint4*)&uw1th[bsrc];
            *(uint4*)&BsL[row * 72 + kc * 8] = *(const uint4*)&uw1tl[bsrc];
        }
        __syncthreads();
#pragma unroll
        for (int kk = 0; kk < 2; ++kk) {
            int koff = kk * 32 + (lane >> 4) * 8;
            bf16x8 ah[2], al[2], bh[2], bl[2];
#pragma unroll
            for (int i = 0; i < 2; i++) {
                int r = (wr * 32 + i * 16 + (lane & 15)) * 72 + koff;
                ah[i] = *(bf16x8*)&AsH[r];
                al[i] = *(bf16x8*)&AsL[r];
            }
#pragma unroll
            for (int j = 0; j < 2; j++) {
                int r = (wc * 32 + j * 16 + (lane & 15)) * 72 + koff;
                bh[j] = *(bf16x8*)&BsH[r];
                bl[j] = *(bf16x8*)&BsL[r];
            }
#pragma unroll
            for (int i = 0; i < 2; i++)
#pragma unroll
                for (int j = 0; j < 2; j++) {
                    acc[i][j] = __builtin_amdgcn_mfma_f32_16x16x32_bf16(ah[i], bh[j], acc[i][j], 0, 0, 0);
                    acc[i][j] = __builtin_amdgcn_mfma_f32_16x16x32_bf16(al[i], bh[j], acc[i][j], 0, 0, 0);
                    acc[i][j] = __builtin_amdgcn_mfma_f32_16x16x32_bf16(ah[i], bl[j], acc[i][j], 0, 0, 0);
                }
        }
    }
    int rloc = (lane >> 4) * 4;
#pragma unroll
    for (int i = 0; i < 2; i++)
#pragma unroll
        for (int j = 0; j < 2; j++) {
            int col = n0 + wc * 32 + j * 16 + (lane & 15);
            float bias = b1[col];
#pragma unroll
            for (int r = 0; r < 4; r++) {
                int m = m0 + wr * 32 + i * 16 + rloc + r;
                float v = fmaxf(acc[i][j][r] + bias, 0.f);
                unsigned short hi, lo;
                split_bf(v, hi, lo);
                Ub_hi[(size_t)m * 256 + col] = hi;
                Ub_lo[(size_t)m * 256 + col] = lo;
            }
        }
}

// ---- h(15360x128) += U @ uw2t^T + b2 ; BM=32 BN=64 (grid 480x2 -> ~3.8 blk/CU) ----
__global__ __launch_bounds__(256) void k_upd2_mf(const unsigned short* __restrict__ Ub_hi,
                                                 const unsigned short* __restrict__ Ub_lo,
                                                 const unsigned short* __restrict__ uw2th,
                                                 const unsigned short* __restrict__ uw2tl,
                                                 const float* __restrict__ b2,
                                                 float* __restrict__ h,
                                                 unsigned short* __restrict__ h_hi,
                                                 unsigned short* __restrict__ h_lo) {
    __shared__ unsigned short AsH[32 * 72], AsL[32 * 72];
    __shared__ unsigned short BsH[64 * 72], BsL[64 * 72];
    int m0 = blockIdx.x * 32, n0 = blockIdx.y * 64;
    int tid = threadIdx.x;
    int lane = tid & 63, wid = tid >> 6;
    int wr = wid >> 1, wc = wid & 1;  // wave covers 16 rows x 32 cols
    f32x4 acc[2] = {};
    for (int k0 = 0; k0 < 256; k0 += 64) {
        __syncthreads();
        {
            int c = tid;  // exactly 256 units for A (32x8)
            int row = c >> 3, kc = c & 7;
            size_t s = (size_t)(m0 + row) * 256 + k0 + kc * 8;
            *(uint4*)&AsH[row * 72 + kc * 8] = *(const uint4*)&Ub_hi[s];
            *(uint4*)&AsL[row * 72 + kc * 8] = *(const uint4*)&Ub_lo[s];
        }
        for (int c = tid; c < 512; c += 256) {
            int row = c >> 3, kc = c & 7;
            size_t bsrc = (size_t)(n0 + row) * 256 + k0 + kc * 8;
            *(uint4*)&BsH[row * 72 + kc * 8] = *(const uint4*)&uw2th[bsrc];
            *(uint4*)&BsL[row * 72 + kc * 8] = *(const uint4*)&uw2tl[bsrc];
        }
        __syncthreads();
#pragma unroll
        for (int kk = 0; kk < 2; ++kk) {
            int koff = kk * 32 + (lane >> 4) * 8;
            int ra = (wr * 16 + (lane & 15)) * 72 + koff;
            bf16x8 ah = *(bf16x8*)&AsH[ra];
            bf16x8 al = *(bf16x8*)&AsL[ra];
#pragma unroll
            for (int j = 0; j < 2; j++) {
                int rb = (wc * 32 + j * 16 + (lane & 15)) * 72 + koff;
                bf16x8 bh = *(bf16x8*)&BsH[rb];
                bf16x8 bl = *(bf16x8*)&BsL[rb];
                acc[j] = __builtin_amdgcn_mfma_f32_16x16x32_bf16(ah, bh, acc[j], 0, 0, 0);
                acc[j] = __builtin_amdgcn_mfma_f32_16x16x32_bf16(al, bh, acc[j], 0, 0, 0);
                acc[j] = __builtin_amdgcn_mfma_f32_16x16x32_bf16(ah, bl, acc[j], 0, 0, 0);
            }
        }
    }
    int rloc = (lane >> 4) * 4;
#pragma unroll
    for (int j = 0; j < 2; j++) {
        int col = n0 + wc * 32 + j * 16 + (lane & 15);
        float bias = b2[col];
#pragma unroll
        for (int r = 0; r < 4; r++) {
            int m = m0 + wr * 16 + rloc + r;
            size_t o = (size_t)m * D + col;
            float v = h[o] + acc[j][r] + bias;
            h[o] = v;
            unsigned short hi, lo;
            split_bf(v, hi, lo);
            h_hi[o] = hi;
            h_lo[o] = lo;
        }
    }
}

// ===== edge pass, 3-way type-aligned split: block=(part, graph) =====
// part 0: q-edges 0..44 (to in [0,15)); parts 1,2: c-edges 45..89 / 90..134 (to in [30,60)).
// M=48 (45 valid), N=128, K=256, BK=64. aggl 30x128. B frags from global (L2-hot).
__global__ __launch_bounds__(256) void k_edge_mf3(const float* __restrict__ H1c,
                                                  const float* __restrict__ uv,
                                                  const int* __restrict__ fr,
                                                  const int* __restrict__ to,
                                                  const float* __restrict__ ef,
                                                  const float* __restrict__ mfi,
                                                  const unsigned short* __restrict__ w2th,
                                                  const unsigned short* __restrict__ w2tl,
                                                  const float* __restrict__ b2,
                                                  float* __restrict__ aggQ,
                                                  float* __restrict__ aggC0,
                                                  float* __restrict__ aggC1) {
    __shared__ unsigned short AsH[48 * 72], AsL[48 * 72];
    __shared__ float aggl[NCC][128];
    __shared__ float uvl[512];
    __shared__ int cfs[48], ctl[48];
    __shared__ float efs[48], ms_[48];
    int part = blockIdx.x;
    int g = blockIdx.y;
    int tid = threadIdx.x;
    int lane = tid & 63, wid = tid >> 6;
    int ebase = g * EPG + part * 45;
    if (tid < 48) {
        if (tid < 45) {
            int f = fr[ebase + tid] - g * 60;
            int t = to[ebase + tid] - g * 60;
            cfs[tid] = g * 45 + (f < 15 ? f : f - 15);
            // store compact to-row alongside (reuse efs slot trick not needed; extra array)
            ctl[tid] = (t < 15) ? t : (t - 30);   // aggl row
            efs[tid] = ef[ebase + tid];
            ms_[tid] = mfi[ebase + tid];
        } else {
            cfs[tid] = g * 45; ctl[tid] = 0; efs[tid] = 0.f; ms_[tid] = 0.f;
        }
    }
    __shared__ int ctc[48];  // compact to-row in H1c
    if (tid < 48) {
        if (tid < 45) {
            int t = to[ebase + tid] - g * 60;
            ctc[tid] = g * 45 + (t < 15 ? t : t - 15);
        } else ctc[tid] = g * 45;
    }
    for (int i = tid; i < 512; i += 256) uvl[i] = uv[i];
    for (int i = tid; i < NCC * 128; i += 256) (&aggl[0][0])[i] = 0.f;
    f32x4 acc[3][2] = {};
    for (int ks = 0; ks < 4; ++ks) {
        __syncthreads();
        // Z = relu(H1[from][k] + H1[to][256+k] + ef*u + v), 48 rows x 64 k, split hi/lo
        for (int c = tid; c < 384; c += 256) {
            int row = c >> 3, kc = c & 7;
            int k = ks * 64 + kc * 8;
            const float* pf = H1c + (size_t)cfs[row] * 512 + k;
            const float* pt = H1c + (size_t)ctc[row] * 512 + 256 + k;
            float e_ = efs[row];
            float4 f0 = *(const float4*)pf, f1 = *(const float4*)(pf + 4);
            float4 t0 = *(const float4*)pt, t1 = *(const float4*)(pt + 4);
            float zf[8] = {f0.x + t0.x, f0.y + t0.y, f0.z + t0.z, f0.w + t0.w,
                           f1.x + t1.x, f1.y + t1.y, f1.z + t1.z, f1.w + t1.w};
            unsigned int ph[4], pl[4];
#pragma unroll
            for (int t = 0; t < 4; t++) {
                float z0 = fmaxf(zf[2 * t]     + e_ * uvl[k + 2 * t]     + uvl[256 + k + 2 * t], 0.f);
                float z1 = fmaxf(zf[2 * t + 1] + e_ * uvl[k + 2 * t + 1] + uvl[256 + k + 2 * t + 1], 0.f);
                unsigned short h0, l0, h1, l1;
                split_bf(z0, h0, l0);
                split_bf(z1, h1, l1);
                ph[t] = (unsigned int)h0 | ((unsigned int)h1 << 16);
                pl[t] = (unsigned int)l0 | ((unsigned int)l1 << 16);
            }
            *(uint4*)&AsH[row * 72 + kc * 8] = make_uint4(ph[0], ph[1], ph[2], ph[3]);
            *(uint4*)&AsL[row * 72 + kc * 8] = make_uint4(pl[0], pl[1], pl[2], pl[3]);
        }
        __syncthreads();
#pragma unroll
        for (int kk = 0; kk < 2; ++kk) {
            int koff = kk * 32 + (lane >> 4) * 8;
            bf16x8 bh[2], bl[2];
#pragma unroll
            for (int j = 0; j < 2; j++) {
                size_t br = (size_t)(wid * 32 + j * 16 + (lane & 15)) * 256 + ks * 64 + koff;
                bh[j] = *(const bf16x8*)&w2th[br];
                bl[j] = *(const bf16x8*)&w2tl[br];
            }
#pragma unroll
            for (int i = 0; i < 3; i++) {
                int r = (i * 16 + (lane & 15)) * 72 + koff;
                bf16x8 ah = *(bf16x8*)&AsH[r];
                bf16x8 al = *(bf16x8*)&AsL[r];
#pragma unroll
                for (int j = 0; j < 2; j++) {
                    acc[i][j] = __builtin_amdgcn_mfma_f32_16x16x32_bf16(ah, bh[j], acc[i][j], 0, 0, 0);
                    acc[i][j] = __builtin_amdgcn_mfma_f32_16x16x32_bf16(al, bh[j], acc[i][j], 0, 0, 0);
                    acc[i][j] = __builtin_amdgcn_mfma_f32_16x16x32_bf16(ah, bl[j], acc[i][j], 0, 0, 0);
                }
            }
        }
    }
    __syncthreads();
    int rloc = (lane >> 4) * 4;
#pragma unroll
    for (int i = 0; i < 3; i++)
#pragma unroll
        for (int j = 0; j < 2; j++) {
            int col = wid * 32 + j * 16 + (lane & 15);
            float bias = b2[col];
#pragma unroll
            for (int r = 0; r < 4; r++) {
                int e = i * 16 + rloc + r;
                if (e < 45) {
                    float val = (acc[i][j][r] + bias) * ms_[e];
                    atomicAdd(&aggl[ctl[e]][col], val);
                }
            }
        }
    __syncthreads();
    if (part == 0) {
        for (int idx = tid; idx < NQQ * 128; idx += 256) {
            int r = idx >> 7, c = idx & 127;
            aggQ[(size_t)(g * NQQ + r) * D + c] = aggl[r][c];
        }
    } else {
        float* dst = (part == 1) ? aggC0 : aggC1;
        for (int idx = tid; idx < NCC * 128; idx += 256) {
            int r = idx >> 7, c = idx & 127;
            dst[(size_t)(g * NCC + r) * D + c] = aggl[r][c];
        }
    }
}

// ---------------- final transform, 45 useful rows per graph -----------------
__global__ __launch_bounds__(64) void k_transform2(const float* __restrict__ h,
                                                   const float* __restrict__ w1,
                                                   const float* __restrict__ b1,
                                                   const float* __restrict__ w2,
                                                   const float* __restrict__ b2,
                                                   float* __restrict__ tall) {
    __shared__ float row[D];
    __shared__ float hid[TT];
    int b = blockIdx.x;
    int g = b / 45, p = b - g * 45;
    int node = g * NPG + (p < NQQ ? p : p + 15);
    int j = threadIdx.x;  // 0..63
    row[j] = h[(size_t)node * D + j];
    row[j + 64] = h[(size_t)node * D + j + 64];
    __syncthreads();
    float s = b1[j];
    for (int k = 0; k < D; k++) s += row[k] * w1[k * TT + j];
    hid[j] = fmaxf(s, 0.f);
    __syncthreads();
    float o = b2[j];
    for (int k = 0; k < TT; k++) o += hid[k] * w2[k * TT + j];
    tall[(size_t)b * TT + j] = o;
}

// ===== per-graph Sinkhorn + score; wave-parallel lse, padded LDS =====
__global__ __launch_bounds__(256) void k_sinkhorn2(const float* __restrict__ h,
                                                   const float* __restrict__ tall,
                                                   float* __restrict__ out) {
    __shared__ float ce[NCC][D];
    __shared__ float tq[NQQ][TT + 2];
    __shared__ float tc[NCC][TT + 2];
    __shared__ float la[NCC][33];
    __shared__ float red[256];
    int g = blockIdx.x;
    int tid = threadIdx.x;
    for (int idx = tid; idx < NCC * D; idx += 256) {
        int c = idx >> 7, d = idx & 127;
        ce[c][d] = h[(size_t)(g * NPG + NCC + c) * D + d];
    }
    for (int idx = tid; idx < 45 * TT; idx += 256) {
        int r = idx >> 6, j = idx & 63;
        float v = tall[(size_t)(g * 45 + r) * TT + j];
        if (r < NQQ) tq[r][j] = v;
        else tc[r - NQQ][j] = v;
    }
    __syncthreads();
    for (int e = tid; e < NCC * NCC; e += 256) {
        int q = e / NCC, c = e % NCC;
        float s = 0.f;
        if (q < NQQ) {
#pragma unroll 4
            for (int k = 0; k < TT; k++) s += tq[q][k] * tc[c][k];
            s *= 10.0f;
        }
        la[q][c] = s;
    }
    __syncthreads();
    int grp = tid >> 3, k8 = tid & 7;
    for (int it = 0; it < SKI; ++it) {
        if (grp < NCC) {
            float v[4], m = -INFINITY;
#pragma unroll
            for (int t = 0; t < 4; t++) {
                int c = k8 * 4 + t;
                v[t] = (c < NCC) ? la[grp][c] : -INFINITY;
                m = fmaxf(m, v[t]);
            }
            m = fmaxf(m, __shfl_xor(m, 1));
            m = fmaxf(m, __shfl_xor(m, 2));
            m = fmaxf(m, __shfl_xor(m, 4));
            float s = 0.f;
#pragma unroll
            for (int t = 0; t < 4; t++)
                if (k8 * 4 + t < NCC) s += __expf(v[t] - m);
            s += __shfl_xor(s, 1);
            s += __shfl_xor(s, 2);
            s += __shfl_xor(s, 4);
            float lse = m + __logf(s);
#pragma unroll
            for (int t = 0; t < 4; t++) {
                int c = k8 * 4 + t;
                if (c < NCC) la[grp][c] = v[t] - lse;
            }
        }
        __syncthreads();
        if (grp < NCC) {
            float v[4], m = -INFINITY;
#pragma unroll
            for (int t = 0; t < 4; t++) {
                int q = k8 * 4 + t;
                v[t] = (q < NCC) ? la[q][grp] : -INFINITY;
                m = fmaxf(m, v[t]);
            }
            m = fmaxf(m, __shfl_xor(m, 1));
            m = fmaxf(m, __shfl_xor(m, 2));
            m = fmaxf(m, __shfl_xor(m, 4));
            float s = 0.f;
#pragma unroll
            for (int t = 0; t < 4; t++)
                if (k8 * 4 + t < NCC) s += __expf(v[t] - m);
            s += __shfl_xor(s, 1);
            s += __shfl_xor(s, 2);
            s += __shfl_xor(s, 4);
            float lse = m + __logf(s);
#pragma unroll
            for (int t = 0; t < 4; t++) {
                int q = k8 * 4 + t;
                if (q < NCC) la[q][grp] = v[t] - lse;
            }
        }
        __syncthreads();
    }
    for (int e = tid; e < NCC * NCC; e += 256) {
        int q = e / NCC, c = e % NCC;
        la[q][c] = __expf(la[q][c]);
    }
    __syncthreads();
    float part = 0.f;
    for (int idx = tid; idx < NCC * D; idx += 256) {
        int q = idx >> 7, d = idx & 127;
        float mv = 0.f;
#pragma unroll 5
        for (int c = 0; c < NCC; c++) mv += la[q][c] * ce[c][d];
        float qv = h[(size_t)(g * NPG + q) * D + d];
        part += fmaxf(qv - mv, 0.f);
    }
    red[tid] = part;
    __syncthreads();
    for (int s2 = 128; s2 > 0; s2 >>= 1) {
        if (tid < s2) red[tid] += red[tid + s2];
        __syncthreads();
    }
    if (tid == 0) out[g] = -red[0];
}

extern "C" void kernel_launch(void* const* d_in, const int* in_sizes, int n_in,
                              void* d_out, int out_size, void* d_ws, size_t ws_size,
                              hipStream_t stream) {
    const float* nf  = (const float*)d_in[0];
    const float* ef  = (const float*)d_in[1];
    const float* mfi = (const float*)d_in[2];
    const float* enw = (const float*)d_in[3];
    const float* enb = (const float*)d_in[4];
    const float* eew = (const float*)d_in[5];
    const float* eeb = (const float*)d_in[6];
    const float* mw1 = (const float*)d_in[7];
    const float* mb1 = (const float*)d_in[8];
    const float* mw2 = (const float*)d_in[9];
    const float* mb2 = (const float*)d_in[10];
    const float* uw1 = (const float*)d_in[11];
    const float* ub1 = (const float*)d_in[12];
    const float* uw2 = (const float*)d_in[13];
    const float* ub2 = (const float*)d_in[14];
    const float* f1w = (const float*)d_in[15];
    const float* f1b = (const float*)d_in[16];
    const float* f2w = (const float*)d_in[17];
    const float* f2b = (const float*)d_in[18];
    const int* fr = (const int*)d_in[19];
    const int* to = (const int*)d_in[20];
    float* out = (float*)d_out;

    // workspace layout
    char* base = (char*)d_ws;
    size_t off = 0;
    float* h = (float*)(base + off);                 off += (size_t)NN * D * 4;
    unsigned short* h_hi = (unsigned short*)(base + off); off += (size_t)NN * D * 2;
    unsigned short* h_lo = (unsigned short*)(base + off); off += (size_t)NN * D * 2;
    // H1c fp32 region; Ub hi/lo pair aliases it (phase-disjoint within an iteration)
    float* H1c = (float*)(base + off);
    unsigned short* Ub_hi = (unsigned short*)H1c;
    unsigned short* Ub_lo = Ub_hi + (size_t)NN * 256;
    off += (size_t)NCR * 512 * 4;
    float* aggQ  = (float*)(base + off); off += (size_t)BATCH * NQQ * D * 4;
    float* aggC0 = (float*)(base + off); off += (size_t)BATCH * NCC * D * 4;
    float* aggC1 = (float*)(base + off); off += (size_t)BATCH * NCC * D * 4;
    unsigned short* w1th = (unsigned short*)(base + off); off += 65536 * 2;
    unsigned short* w1tl = (unsigned short*)(base + off); off += 65536 * 2;
    unsigned short* w2th = (unsigned short*)(base + off); off += 32768 * 2;
    unsigned short* w2tl = (unsigned short*)(base + off); off += 32768 * 2;
    unsigned short* uw1th = (unsigned short*)(base + off); off += 65536 * 2;
    unsigned short* uw1tl = (unsigned short*)(base + off); off += 65536 * 2;
    unsigned short* uw2th = (unsigned short*)(base + off); off += 32768 * 2;
    unsigned short* uw2tl = (unsigned short*)(base + off); off += 32768 * 2;
    float* uv = (float*)(base + off); off += 512 * 4;
    float* tall = (float*)(base + off);  // NCR*64 f32 (2.95MB), dedicated

    k_encode<<<(NN * D + 255) / 256, 256, 0, stream>>>(nf, enw, enb, h, h_hi, h_lo);
    k_prep_uv<<<1, 256, 0, stream>>>(eew, eeb, mw1, mb1, uv);
    k_prep_w<<<768, 256, 0, stream>>>(mw1, mw2, uw1, uw2, w1th, w1tl, w2th, w2tl,
                                      uw1th, uw1tl, uw2th, uw2tl);

    for (int it = 0; it < NPROP; ++it) {
        k_h1c_mf<<<dim3(NCR / 64, 8), 256, 0, stream>>>(h_hi, h_lo, w1th, w1tl, H1c);
        k_edge_mf3<<<dim3(3, BATCH), 256, 0, stream>>>(H1c, uv, fr, to, ef, mfi,
                                                       w2th, w2tl, mb2,
                                                       aggQ, aggC0, aggC1);
        k_upd1_mf<<<dim3(NN / 64, 4), 256, 0, stream>>>(aggQ, aggC0, aggC1, h_hi, h_lo,
                                                        uw1th, uw1tl, ub1, Ub_hi, Ub_lo);
        k_upd2_mf<<<dim3(NN / 32, 2), 256, 0, stream>>>(Ub_hi, Ub_lo, uw2th, uw2tl,
                                                        ub2, h, h_hi, h_lo);
    }

    k_transform2<<<NCR, 64, 0, stream>>>(h, f1w, f1b, f2w, f2b, tall);
    k_sinkhorn2<<<BATCH, 256, 0, stream>>>(h, tall, out);
}